// Round 7
// baseline (182.973 us; speedup 1.0000x reference)
//
#include <hip/hip_runtime.h>
#include <math.h>

namespace {

typedef __bf16 bf16_t;
typedef bf16_t bf16x8 __attribute__((ext_vector_type(8)));
typedef bf16_t bf16x4 __attribute__((ext_vector_type(4)));
typedef bf16_t bf16x2 __attribute__((ext_vector_type(2)));
typedef float f32x4 __attribute__((ext_vector_type(4)));

constexpr int L = 1024;
constexpr int H = 8;
constexpr int E = 64;
constexpr int HE = H * E;            // 512
constexpr int BH = 16;
constexpr size_t PL = (size_t)BH * L * E;  // 1,048,576 elems per plane
constexpr float LOG2E = 1.4426950408889634f;
constexpr float LN2 = 0.6931471805599453f;

__device__ __forceinline__ float rcp_fast(float x) { return __builtin_amdgcn_rcpf(x); }
__device__ __forceinline__ float exp2_fast(float x) { return __builtin_amdgcn_exp2f(x); }
__device__ __forceinline__ float log2_fast(float x) { return __builtin_amdgcn_logf(x); }
__device__ __forceinline__ f32x4 mfma16(bf16x8 a, bf16x8 b, f32x4 c) {
  return __builtin_amdgcn_mfma_f32_16x16x32_bf16(a, b, c, 0, 0, 0);
}
__device__ __forceinline__ void split4(float4 x, bf16x4& hv, bf16x4& lv) {
  hv[0] = (bf16_t)x.x; lv[0] = (bf16_t)(x.x - (float)hv[0]);
  hv[1] = (bf16_t)x.y; lv[1] = (bf16_t)(x.y - (float)hv[1]);
  hv[2] = (bf16_t)x.z; lv[2] = (bf16_t)(x.z - (float)hv[2]);
  hv[3] = (bf16_t)x.w; lv[3] = (bf16_t)(x.w - (float)hv[3]);
}

// ===========================================================================
// Prep + zero-init fused. Blocks [0,256): Q,K -> bf16 hi/lo planes
// [bh][l][e], V -> VT bf16 [bh][e][s] (16 bh x 16 l-chunks of 64).
// Blocks [256,1296): zero Vout (1M f32) + entr (16K f32).
// ===========================================================================
__global__ __launch_bounds__(256) void k_prep(
    const float* __restrict__ q, const float* __restrict__ k,
    const float* __restrict__ v, bf16_t* __restrict__ ws,
    float* __restrict__ Vout, float* __restrict__ entr)
{
  const int bid = blockIdx.x;
  if (bid >= 256) {  // zero-init branch
    const int idx = (bid - 256) * 256 + threadIdx.x;
    const float4 z = make_float4(0.f, 0.f, 0.f, 0.f);
    if (idx < 262144) *(float4*)(Vout + (size_t)idx * 4) = z;
    else              *(float4*)(entr + (size_t)(idx - 262144) * 4) = z;
    return;
  }
  bf16_t* Qh = ws;
  bf16_t* Ql = ws + PL;
  bf16_t* Kh = ws + 2 * PL;
  bf16_t* Kl = ws + 3 * PL;
  bf16_t* VT = ws + 4 * PL;
  const int bh = bid >> 4, chunk = bid & 15;   // 64-row chunks
  const int b = bh >> 3, h = bh & 7;
  const int tid = threadIdx.x, t8 = tid >> 4, c4 = tid & 15;
  __shared__ bf16_t Vb[64][72];  // [e][l-local 64]

#pragma unroll
  for (int pass = 0; pass < 4; ++pass) {
    const int row = chunk * 64 + pass * 16 + t8;
    const size_t gin = ((size_t)(b * L + row) * H + h) * E + c4 * 4;
    const size_t gout = ((size_t)bh * L + row) * E + c4 * 4;
    float4 q4 = *(const float4*)(q + gin);
    float4 k4 = *(const float4*)(k + gin);
    float4 v4 = *(const float4*)(v + gin);
    bf16x4 hv, lv;
    split4(q4, hv, lv);
    *(bf16x4*)(Qh + gout) = hv; *(bf16x4*)(Ql + gout) = lv;
    split4(k4, hv, lv);
    *(bf16x4*)(Kh + gout) = hv; *(bf16x4*)(Kl + gout) = lv;
    const int sl = pass * 16 + t8;
    Vb[c4 * 4 + 0][sl] = (bf16_t)v4.x;
    Vb[c4 * 4 + 1][sl] = (bf16_t)v4.y;
    Vb[c4 * 4 + 2][sl] = (bf16_t)v4.z;
    Vb[c4 * 4 + 3][sl] = (bf16_t)v4.w;
  }
  __syncthreads();
#pragma unroll
  for (int pass = 0; pass < 2; ++pass) {
    const int idx = pass * 256 + tid;
    const int e = idx >> 3, ch = idx & 7;
    bf16x8 val = *(const bf16x8*)&Vb[e][ch * 8];
    *(bf16x8*)(VT + ((size_t)bh * E + e) * L + chunk * 64 + ch * 8) = val;
  }
}

// ===========================================================================
// Main fused kernel, BARRIER-FREE K-loop. grid (32 lt, 16 bh, 4 zb), 256 thr
// (4 waves). Wave w: l-half (w&1)*16 rows, s-half (w>>1)*32 of each s-tile.
// No block-shared staging: B-fragments (K/Q hi-lo rows, VT rows) are 16B
// per-lane loads straight from the L2-resident planes. LDS only holds the
// per-wave attL D->A exchange and the epilogue reduction (~14 KB), so the
// K-loop needs no __syncthreads at all; occupancy is VGPR-bound.
// ===========================================================================
__global__ __launch_bounds__(256, 3) void k_main(
    const bf16_t* __restrict__ ws,
    float* __restrict__ Vout, float* __restrict__ attg, float* __restrict__ entr,
    const float* __restrict__ p_lgg, const float* __restrict__ p_ltg,
    const float* __restrict__ p_lgd, const float* __restrict__ p_ltd)
{
  const bf16_t* Qh = ws;
  const bf16_t* Ql = ws + PL;
  const bf16_t* Kh = ws + 2 * PL;
  const bf16_t* Kl = ws + 3 * PL;
  const bf16_t* VT = ws + 4 * PL;

  __shared__ bf16_t attL[4][16][40];   // per-wave P exchange (5120 B)
  __shared__ float red[32][68];        // epilogue s-half reduction (8704 B)

  const int tid = threadIdx.x;
  const int w = tid >> 6, lane = tid & 63;
  const int c = lane & 15, qd = lane >> 4;
  const int lh = w & 1, sh = w >> 1;
  const int lt = blockIdx.x, bh = blockIdx.y, zb = blockIdx.z;
  const int b = bh >> 3, h = bh & 7;
  const int l0 = lt * 32;

  const float gg = fminf(fmaxf(__expf(p_lgg[0]), 1e-3f), 20.0f);
  const float tg = fminf(fmaxf(__expf(p_ltg[0]), 1e-3f), 10.0f);
  const float gd = fminf(fmaxf(__expf(p_lgd[0]), 1e-3f), 20.0f);
  const float td = fminf(fmaxf(__expf(p_ltd[0]), 1e-3f), 10.0f);
  // Folded transform coefficients (scores 1/8 * symmetrize 1/2 = 1/16):
  //   tanh(z) = 1 - 2/(exp2(2*log2e*z)+1); sigm(z) = 1/(1+exp2(-log2e*z))
  const float A1 = 0.125f * (1.0f / tg) * LOG2E;
  const float A2 = 0.125f * (1.0f / td) * LOG2E;
  const float A3 = 0.125f * gd * (1.0f / td) * LOG2E;
  const float G1 = -gg * LOG2E;
  const float G2 = -gd * LOG2E;

  // A-fragments (held all loop): Q/K hi+lo, row l0 + lh*16 + c
  bf16x8 qaf[2][2], kaf[2][2];
  {
    const size_t aro = ((size_t)bh * L + l0 + lh * 16 + c) * E;
#pragma unroll
    for (int ks = 0; ks < 2; ++ks) {
      qaf[ks][0] = *(const bf16x8*)(Qh + aro + ks * 32 + qd * 8);
      qaf[ks][1] = *(const bf16x8*)(Ql + aro + ks * 32 + qd * 8);
      kaf[ks][0] = *(const bf16x8*)(Kh + aro + ks * 32 + qd * 8);
      kaf[ks][1] = *(const bf16x8*)(Kl + aro + ks * 32 + qd * 8);
    }
  }

  f32x4 accv[4] = {};
  float ent[4] = {0.f, 0.f, 0.f, 0.f};  // accumulated in log2 domain

#pragma unroll
  for (int it = 0; it < 4; ++it) {
    const int s0 = (zb * 4 + it) * 64;

    // ---- B-fragment global loads (16B/lane, L1/L2-hot) ----
    // B-row for T1/T2: s0 + sh*32 + nt*16 + c ; k-cols ks*32 + qd*8
    bf16x8 kbh[2][2], kbl[2][2], qbh[2][2], qbl[2][2];
    const size_t bro = ((size_t)bh * L + s0 + sh * 32 + c) * E + qd * 8;
#pragma unroll
    for (int nt = 0; nt < 2; ++nt) {
#pragma unroll
      for (int ks = 0; ks < 2; ++ks) {
        const size_t o = bro + (size_t)nt * 16 * E + ks * 32;
        kbh[nt][ks] = *(const bf16x8*)(Kh + o);
        kbl[nt][ks] = *(const bf16x8*)(Kl + o);
        qbh[nt][ks] = *(const bf16x8*)(Qh + o);
        qbl[nt][ks] = *(const bf16x8*)(Ql + o);
      }
    }
    bf16x8 vbv[4];
#pragma unroll
    for (int ne = 0; ne < 4; ++ne)
      vbv[ne] = *(const bf16x8*)(VT + ((size_t)bh * E + ne * 16 + c) * L +
                                 s0 + sh * 32 + qd * 8);

    // ---- dual QK^T: T1 = Q[l]·K[s], T2 = K[l]·Q[s] (same C-layout).
    // Term order matched so the diagonal cancels bitwise (Aa == 0).
    f32x4 acc1[2] = {}, acc2[2] = {};
#pragma unroll
    for (int nt = 0; nt < 2; ++nt) {
#pragma unroll
      for (int ks = 0; ks < 2; ++ks) {
        acc1[nt] = mfma16(qaf[ks][0], kbh[nt][ks], acc1[nt]);
        acc1[nt] = mfma16(qaf[ks][0], kbl[nt][ks], acc1[nt]);
        acc1[nt] = mfma16(qaf[ks][1], kbh[nt][ks], acc1[nt]);
        acc2[nt] = mfma16(kaf[ks][0], qbh[nt][ks], acc2[nt]);
        acc2[nt] = mfma16(kaf[ks][1], qbh[nt][ks], acc2[nt]);
        acc2[nt] = mfma16(kaf[ks][0], qbl[nt][ks], acc2[nt]);
      }
    }

    // ---- transform (register-local), att NT-store, attL, entropy ----
    float* arow = attg + ((size_t)bh * L + l0 + lh * 16 + qd * 4) * L + s0 + sh * 32;
#pragma unroll
    for (int nt = 0; nt < 2; ++nt) {
#pragma unroll
      for (int r = 0; r < 4; ++r) {
        float u = acc1[nt][r] + acc2[nt][r];        // 16*S_sym
        float d = acc1[nt][r] - acc2[nt][r];        // 16*A_anti
        float th1 = 1.f - 2.f * rcp_fast(exp2_fast(u * A1) + 1.f);
        float gate = rcp_fast(1.f + exp2_fast(th1 * G1));
        float th2 = 1.f - 2.f * rcp_fast(exp2_fast(d * A2) + 1.f);
        float dir  = rcp_fast(1.f + exp2_fast(th2 * G2));
        float t    = 1.f - 2.f * rcp_fast(exp2_fast(d * A3) + 1.f);
        float a = fmaxf(t, 0.0f) * gate * dir;
        ent[r] -= a * log2_fast(fmaxf(a, 1e-8f));
        __builtin_nontemporal_store(a, arow + (size_t)r * L + nt * 16 + c);
        attL[w][qd * 4 + r][nt * 16 + c] = (bf16_t)a;
      }
    }
    // wave-local D-layout -> A-layout exchange (no cross-wave sharing)
    __threadfence_block();

    // ---- PV ----
    bf16x8 af = *(const bf16x8*)&attL[w][c][qd * 8];
#pragma unroll
    for (int ne = 0; ne < 4; ++ne)
      accv[ne] = mfma16(af, vbv[ne], accv[ne]);
  }

  // ---- epilogue: combine s-halves, atomic into global (zb-split blocks) ----
  if (sh == 1) {
#pragma unroll
    for (int ne = 0; ne < 4; ++ne)
#pragma unroll
      for (int r = 0; r < 4; ++r)
        red[lh * 16 + qd * 4 + r][ne * 16 + c] = accv[ne][r];
  }
  __syncthreads();
  if (sh == 0) {
#pragma unroll
    for (int ne = 0; ne < 4; ++ne)
#pragma unroll
      for (int r = 0; r < 4; ++r) {
        float val = accv[ne][r] + red[lh * 16 + qd * 4 + r][ne * 16 + c];
        atomicAdd(Vout + ((size_t)(b * L + l0 + lh * 16 + qd * 4 + r) * H + h) * E +
                      ne * 16 + c,
                  val);
      }
  }
#pragma unroll
  for (int r = 0; r < 4; ++r) {
    float e = ent[r];
    e += __shfl_xor(e, 1);
    e += __shfl_xor(e, 2);
    e += __shfl_xor(e, 4);
    e += __shfl_xor(e, 8);
    if (c == 0)
      atomicAdd(entr + (size_t)bh * L + l0 + lh * 16 + qd * 4 + r, e * LN2);
  }
}

// ===========================================================================
// Fallback (R2 kernel) if ws_size is too small for the planes.
// ===========================================================================
__device__ __forceinline__ float tanh_fast(float x) {
  return 1.0f - 2.0f * rcp_fast(__expf(2.0f * x) + 1.0f);
}
__device__ __forceinline__ float sigm_fast(float x) {
  return rcp_fast(1.0f + __expf(-x));
}
__device__ __forceinline__ void split_store(bf16_t* hi, bf16_t* lo, float4 x) {
  bf16x4 hv, lv;
  split4(x, hv, lv);
  *(bf16x4*)hi = hv;
  *(bf16x4*)lo = lv;
}

__global__ __launch_bounds__(128, 1) void fused_attn(
    const float* __restrict__ q, const float* __restrict__ kk,
    const float* __restrict__ v,
    float* __restrict__ Vout, float* __restrict__ attg, float* __restrict__ entr,
    const float* __restrict__ p_lgg, const float* __restrict__ p_ltg,
    const float* __restrict__ p_lgd, const float* __restrict__ p_ltd)
{
  constexpr int TM = 32;
  __shared__ bf16_t Qa_hi[TM][72], Qa_lo[TM][72];
  __shared__ bf16_t Ka_hi[TM][72], Ka_lo[TM][72];
  __shared__ bf16_t KQ_hi[64][72], KQ_lo[64][72];
  __shared__ bf16_t Vts[64][72];
  __shared__ float  T2ex[2][64][17];
  __shared__ bf16_t attLs[2][16][72];

  const int tid = threadIdx.x;
  const int w = tid >> 6;
  const int lane = tid & 63;
  const int c = lane & 15;
  const int qd = lane >> 4;
  const int t8 = tid >> 4;
  const int c4 = tid & 15;
  const int lt = blockIdx.x;
  const int bh = blockIdx.y;
  const int b = bh >> 3, h = bh & 7;
  const int l0 = lt * TM;

  const float gg = fminf(fmaxf(__expf(p_lgg[0]), 1e-3f), 20.0f);
  const float tg = fminf(fmaxf(__expf(p_ltg[0]), 1e-3f), 10.0f);
  const float gd = fminf(fmaxf(__expf(p_lgd[0]), 1e-3f), 20.0f);
  const float td = fminf(fmaxf(__expf(p_ltd[0]), 1e-3f), 10.0f);
  const float inv_tg = 1.0f / tg;
  const float inv_td = 1.0f / td;
  const float gd_inv_td = gd * inv_td;

  const float* qlbase = q  + ((size_t)(b * L + l0) * H + h) * E;
  const float* qsbase = q  + ((size_t)b * L * H + h) * E;
  const float* kbase  = kk + ((size_t)b * L * H + h) * E;
  const float* vbase  = v  + ((size_t)b * L * H + h) * E;

#pragma unroll
  for (int i = 0; i < 4; ++i) {
    int r = t8 + 8 * i;
    float4 qa = *(const float4*)(qlbase + (size_t)r * HE + c4 * 4);
    float4 ka = *(const float4*)(kbase + (size_t)(l0 + r) * HE + c4 * 4);
    split_store(&Qa_hi[r][c4 * 4], &Qa_lo[r][c4 * 4], qa);
    split_store(&Ka_hi[r][c4 * 4], &Ka_lo[r][c4 * 4], ka);
  }

  float4 kpre[8], qpre[8];
  float vpre[32];
#pragma unroll
  for (int i = 0; i < 8; ++i)
    kpre[i] = *(const float4*)(kbase + (size_t)(t8 + 8 * i) * HE + c4 * 4);
#pragma unroll
  for (int i = 0; i < 8; ++i)
    qpre[i] = *(const float4*)(qsbase + (size_t)(t8 + 8 * i) * HE + c4 * 4);
#pragma unroll
  for (int j = 0; j < 32; ++j)
    vpre[j] = vbase[(size_t)(w * 32 + j) * HE + lane];

  __syncthreads();

  bf16x8 qaf[2][2], kaf[2][2];
#pragma unroll
  for (int ks = 0; ks < 2; ++ks) {
    qaf[ks][0] = *(const bf16x8*)&Qa_hi[w * 16 + c][ks * 32 + qd * 8];
    qaf[ks][1] = *(const bf16x8*)&Qa_lo[w * 16 + c][ks * 32 + qd * 8];
    kaf[ks][0] = *(const bf16x8*)&Ka_hi[w * 16 + c][ks * 32 + qd * 8];
    kaf[ks][1] = *(const bf16x8*)&Ka_lo[w * 16 + c][ks * 32 + qd * 8];
  }

  f32x4 accv[4] = {};
  float ent[4] = {0.f, 0.f, 0.f, 0.f};
  const int gl_base = l0 + w * 16 + qd * 4;

  for (int it = 0; it < 16; ++it) {
    const int s0 = it * 64;
    const int snext = ((it + 1) & 15) * 64;

    __syncthreads();
#pragma unroll
    for (int i = 0; i < 8; ++i) {
      int r = t8 + 8 * i;
      split_store(&KQ_hi[r][c4 * 4], &KQ_lo[r][c4 * 4], kpre[i]);
    }
#pragma unroll
    for (int j = 0; j < 16; ++j) {
      bf16x2 p;
      p[0] = (bf16_t)vpre[2 * j];
      p[1] = (bf16_t)vpre[2 * j + 1];
      *(bf16x2*)&Vts[lane][w * 32 + 2 * j] = p;
    }
    __syncthreads();

#pragma unroll
    for (int i = 0; i < 8; ++i)
      kpre[i] = *(const float4*)(kbase + (size_t)(snext + t8 + 8 * i) * HE + c4 * 4);
#pragma unroll
    for (int j = 0; j < 32; ++j)
      vpre[j] = vbase[(size_t)(snext + w * 32 + j) * HE + lane];

    f32x4 acc1[4] = {};
#pragma unroll
    for (int nt = 0; nt < 4; ++nt) {
#pragma unroll
      for (int ks = 0; ks < 2; ++ks) {
        bf16x8 bhv = *(const bf16x8*)&KQ_hi[nt * 16 + c][ks * 32 + qd * 8];
        bf16x8 blv = *(const bf16x8*)&KQ_lo[nt * 16 + c][ks * 32 + qd * 8];
        acc1[nt] = mfma16(qaf[ks][0], bhv, acc1[nt]);
        acc1[nt] = mfma16(qaf[ks][0], blv, acc1[nt]);
        acc1[nt] = mfma16(qaf[ks][1], bhv, acc1[nt]);
      }
    }
    __syncthreads();

#pragma unroll
    for (int i = 0; i < 8; ++i) {
      int r = t8 + 8 * i;
      split_store(&KQ_hi[r][c4 * 4], &KQ_lo[r][c4 * 4], qpre[i]);
    }
    __syncthreads();

#pragma unroll
    for (int i = 0; i < 8; ++i)
      qpre[i] = *(const float4*)(qsbase + (size_t)(snext + t8 + 8 * i) * HE + c4 * 4);

    f32x4 acc2[4] = {};
#pragma unroll
    for (int mt = 0; mt < 4; ++mt) {
#pragma unroll
      for (int ks = 0; ks < 2; ++ks) {
        bf16x8 ahv = *(const bf16x8*)&KQ_hi[mt * 16 + c][ks * 32 + qd * 8];
        bf16x8 alv = *(const bf16x8*)&KQ_lo[mt * 16 + c][ks * 32 + qd * 8];
        acc2[mt] = mfma16(ahv, kaf[ks][0], acc2[mt]);
        acc2[mt] = mfma16(ahv, kaf[ks][1], acc2[mt]);
        acc2[mt] = mfma16(alv, kaf[ks][0], acc2[mt]);
      }
    }

#pragma unroll
    for (int mt = 0; mt < 4; ++mt)
#pragma unroll
      for (int r = 0; r < 4; ++r)
        T2ex[w][mt * 16 + qd * 4 + r][c] = acc2[mt][r];
    __syncthreads();

    float* attrow0 = attg + ((size_t)bh * L + gl_base) * L + s0;
#pragma unroll
    for (int nt = 0; nt < 4; ++nt) {
#pragma unroll
      for (int r = 0; r < 4; ++r) {
        float x = 0.125f * acc1[nt][r];
        float y = 0.125f * T2ex[w][nt * 16 + c][qd * 4 + r];
        float Ss = 0.5f * (x + y);
        float Aa = 0.5f * (x - y);
        float gate = sigm_fast(gg * tanh_fast(Ss * inv_tg));
        float dir  = sigm_fast(gd * tanh_fast(Aa * inv_td));
        float t    = tanh_fast(Aa * gd_inv_td);
        float a = fmaxf(t, 0.0f) * gate * dir;
        ent[r] -= a * __logf(fmaxf(a, 1e-8f));
        attrow0[(size_t)r * L + nt * 16 + c] = a;
        attLs[w][qd * 4 + r][nt * 16 + c] = (bf16_t)a;
      }
    }
    __syncthreads();

#pragma unroll
    for (int ks = 0; ks < 2; ++ks) {
      bf16x8 af = *(const bf16x8*)&attLs[w][c][ks * 32 + qd * 8];
#pragma unroll
      for (int ne = 0; ne < 4; ++ne) {
        bf16x8 bfv = *(const bf16x8*)&Vts[ne * 16 + c][ks * 32 + qd * 8];
        accv[ne] = mfma16(af, bfv, accv[ne]);
      }
    }
  }

#pragma unroll
  for (int r = 0; r < 4; ++r) {
    float* vb = Vout + ((size_t)(b * L + gl_base + r) * H + h) * E;
#pragma unroll
    for (int ne = 0; ne < 4; ++ne) vb[ne * 16 + c] = accv[ne][r];
    float e4 = ent[r];
    e4 += __shfl_xor(e4, 1);
    e4 += __shfl_xor(e4, 2);
    e4 += __shfl_xor(e4, 4);
    e4 += __shfl_xor(e4, 8);
    if (c == 0) entr[(size_t)bh * L + gl_base + r] = e4;
  }
}

}  // namespace

extern "C" void kernel_launch(void* const* d_in, const int* in_sizes, int n_in,
                              void* d_out, int out_size, void* d_ws, size_t ws_size,
                              hipStream_t stream) {
  const float* q = (const float*)d_in[0];
  const float* k = (const float*)d_in[1];
  const float* v = (const float*)d_in[2];
  const float* p_lgg = (const float*)d_in[7];
  const float* p_ltg = (const float*)d_in[8];
  const float* p_lgd = (const float*)d_in[9];
  const float* p_ltd = (const float*)d_in[10];

  float* Vout = (float*)d_out;          // (B,L,H,E)   1,048,576
  float* att  = Vout + 1048576;         // (B,H,L,S)  16,777,216
  float* entr = att + 16777216;         // (B,H,L)        16,384

  const size_t need = 5 * PL * sizeof(bf16_t);  // 10,485,760 B
  if (ws_size >= need) {
    bf16_t* ws = (bf16_t*)d_ws;
    k_prep<<<dim3(1296), 256, 0, stream>>>(q, k, v, ws, Vout, entr);
    k_main<<<dim3(32, 16, 4), 256, 0, stream>>>(
        ws, Vout, att, entr, p_lgg, p_ltg, p_lgd, p_ltd);
  } else {
    fused_attn<<<dim3(32, 16), 128, 0, stream>>>(
        q, k, v, Vout, att, entr, p_lgg, p_ltg, p_lgd, p_ltd);
  }
}

// Round 8
// 136.876 us; speedup vs baseline: 1.3368x; 1.3368x over previous
//
#include <hip/hip_runtime.h>
#include <math.h>

namespace {

typedef __bf16 bf16_t;
typedef bf16_t bf16x8 __attribute__((ext_vector_type(8)));
typedef bf16_t bf16x4 __attribute__((ext_vector_type(4)));
typedef bf16_t bf16x2 __attribute__((ext_vector_type(2)));
typedef float f32x4 __attribute__((ext_vector_type(4)));

constexpr int L = 1024;
constexpr int H = 8;
constexpr int E = 64;
constexpr int HE = H * E;            // 512
constexpr int BH = 16;
constexpr size_t PL = (size_t)BH * L * E;  // 1,048,576 elems per plane
constexpr float LOG2E = 1.4426950408889634f;
constexpr float LN2 = 0.6931471805599453f;

__device__ __forceinline__ float rcp_fast(float x) { return __builtin_amdgcn_rcpf(x); }
__device__ __forceinline__ float exp2_fast(float x) { return __builtin_amdgcn_exp2f(x); }
__device__ __forceinline__ float log2_fast(float x) { return __builtin_amdgcn_logf(x); }
__device__ __forceinline__ f32x4 mfma16(bf16x8 a, bf16x8 b, f32x4 c) {
  return __builtin_amdgcn_mfma_f32_16x16x32_bf16(a, b, c, 0, 0, 0);
}
__device__ __forceinline__ void split4(float4 x, bf16x4& hv, bf16x4& lv) {
  hv[0] = (bf16_t)x.x; lv[0] = (bf16_t)(x.x - (float)hv[0]);
  hv[1] = (bf16_t)x.y; lv[1] = (bf16_t)(x.y - (float)hv[1]);
  hv[2] = (bf16_t)x.z; lv[2] = (bf16_t)(x.z - (float)hv[2]);
  hv[3] = (bf16_t)x.w; lv[3] = (bf16_t)(x.w - (float)hv[3]);
}

// ===========================================================================
// Prep + zero-init fused. Blocks [0,256): Q,K -> bf16 hi/lo planes
// [bh][l][e], V -> VT bf16 [bh][e][s]. Blocks [256,1296): zero Vout + entr.
// ===========================================================================
__global__ __launch_bounds__(256) void k_prep(
    const float* __restrict__ q, const float* __restrict__ k,
    const float* __restrict__ v, bf16_t* __restrict__ ws,
    float* __restrict__ Vout, float* __restrict__ entr)
{
  const int bid = blockIdx.x;
  if (bid >= 256) {  // zero-init branch
    const int idx = (bid - 256) * 256 + threadIdx.x;
    const float4 z = make_float4(0.f, 0.f, 0.f, 0.f);
    if (idx < 262144) *(float4*)(Vout + (size_t)idx * 4) = z;
    else              *(float4*)(entr + (size_t)(idx - 262144) * 4) = z;
    return;
  }
  bf16_t* Qh = ws;
  bf16_t* Ql = ws + PL;
  bf16_t* Kh = ws + 2 * PL;
  bf16_t* Kl = ws + 3 * PL;
  bf16_t* VT = ws + 4 * PL;
  const int bh = bid >> 4, chunk = bid & 15;   // 64-row chunks
  const int b = bh >> 3, h = bh & 7;
  const int tid = threadIdx.x, t8 = tid >> 4, c4 = tid & 15;
  __shared__ bf16_t Vb[64][72];  // [e][l-local 64]

#pragma unroll
  for (int pass = 0; pass < 4; ++pass) {
    const int row = chunk * 64 + pass * 16 + t8;
    const size_t gin = ((size_t)(b * L + row) * H + h) * E + c4 * 4;
    const size_t gout = ((size_t)bh * L + row) * E + c4 * 4;
    float4 q4 = *(const float4*)(q + gin);
    float4 k4 = *(const float4*)(k + gin);
    float4 v4 = *(const float4*)(v + gin);
    bf16x4 hv, lv;
    split4(q4, hv, lv);
    *(bf16x4*)(Qh + gout) = hv; *(bf16x4*)(Ql + gout) = lv;
    split4(k4, hv, lv);
    *(bf16x4*)(Kh + gout) = hv; *(bf16x4*)(Kl + gout) = lv;
    const int sl = pass * 16 + t8;
    Vb[c4 * 4 + 0][sl] = (bf16_t)v4.x;
    Vb[c4 * 4 + 1][sl] = (bf16_t)v4.y;
    Vb[c4 * 4 + 2][sl] = (bf16_t)v4.z;
    Vb[c4 * 4 + 3][sl] = (bf16_t)v4.w;
  }
  __syncthreads();
#pragma unroll
  for (int pass = 0; pass < 2; ++pass) {
    const int idx = pass * 256 + tid;
    const int e = idx >> 3, ch = idx & 7;
    bf16x8 val = *(const bf16x8*)&Vb[e][ch * 8];
    *(bf16x8*)(VT + ((size_t)bh * E + e) * L + chunk * 64 + ch * 8) = val;
  }
}

// ===========================================================================
// Main fused kernel, 2-barrier K-loop with SHIELDED prefetch.
// grid (32 lt, 16 bh, 4 zb), 256 thr (4 waves). Wave w: l-half (w&1)*16,
// s-half (w>>1)*32. Separate LDS buffers for Kh/Kl/Qh/Ql/Vt (no phase reuse)
// -> 2 __syncthreads per s-tile. Prefetch for it+1 issued right AFTER the
// staging barrier so the compiler's vmcnt(0)-before-barrier drain lands a
// full compute phase (~700cy) later — latency hidden (R6 bug: prefetch was
// issued right BEFORE a barrier, drained instantly). attL wave-local
// exchange uses a raw `s_waitcnt lgkmcnt(0)` (LDS-only; R7's
// __threadfence_block also drained vmcnt -> serialized everything).
// ===========================================================================
__global__ __launch_bounds__(256, 3) void k_main(
    const bf16_t* __restrict__ ws,
    float* __restrict__ Vout, float* __restrict__ attg, float* __restrict__ entr,
    const float* __restrict__ p_lgg, const float* __restrict__ p_ltg,
    const float* __restrict__ p_lgd, const float* __restrict__ p_ltd)
{
  const bf16_t* Qh = ws;
  const bf16_t* Ql = ws + PL;
  const bf16_t* Kh = ws + 2 * PL;
  const bf16_t* Kl = ws + 3 * PL;
  const bf16_t* VT = ws + 4 * PL;

  // LDS layout (51,200 B): Kh 0 | Kl 9216 | Qh 18432 | Ql 27648 | Vt 36864 |
  // attL 46080 (5120). Epilogue `red` aliases offset 0.
  __shared__ __align__(16) char smem[51200];
  bf16_t (*Kh_s)[72] = (bf16_t(*)[72])(smem);
  bf16_t (*Kl_s)[72] = (bf16_t(*)[72])(smem + 9216);
  bf16_t (*Qh_s)[72] = (bf16_t(*)[72])(smem + 18432);
  bf16_t (*Ql_s)[72] = (bf16_t(*)[72])(smem + 27648);
  bf16_t (*Vt_s)[72] = (bf16_t(*)[72])(smem + 36864);
  bf16_t (*attL)[40] = (bf16_t(*)[40])(smem + 46080);  // [64][40]: wave w rows w*16..+15

  const int tid = threadIdx.x;
  const int w = tid >> 6, lane = tid & 63;
  const int c = lane & 15, qd = lane >> 4;
  const int lh = w & 1, sh = w >> 1;
  const int lt = blockIdx.x, bh = blockIdx.y, zb = blockIdx.z;
  const int b = bh >> 3, h = bh & 7;
  const int l0 = lt * 32;

  const float gg = fminf(fmaxf(__expf(p_lgg[0]), 1e-3f), 20.0f);
  const float tg = fminf(fmaxf(__expf(p_ltg[0]), 1e-3f), 10.0f);
  const float gd = fminf(fmaxf(__expf(p_lgd[0]), 1e-3f), 20.0f);
  const float td = fminf(fmaxf(__expf(p_ltd[0]), 1e-3f), 10.0f);
  // Folded coefficients (scores 1/8 * symmetrize 1/2 = 1/16):
  const float A1 = 0.125f * (1.0f / tg) * LOG2E;
  const float A2 = 0.125f * (1.0f / td) * LOG2E;
  const float A3 = 0.125f * gd * (1.0f / td) * LOG2E;
  const float G1 = -gg * LOG2E, G1m2 = -2.0f * G1;
  const float G2 = -gd * LOG2E, G2m2 = -2.0f * G2;

  // A-fragments (held all loop): Q/K hi+lo, row l0 + lh*16 + c
  bf16x8 qaf[2][2], kaf[2][2];
  {
    const size_t aro = ((size_t)bh * L + l0 + lh * 16 + c) * E;
#pragma unroll
    for (int ks = 0; ks < 2; ++ks) {
      qaf[ks][0] = *(const bf16x8*)(Qh + aro + ks * 32 + qd * 8);
      qaf[ks][1] = *(const bf16x8*)(Ql + aro + ks * 32 + qd * 8);
      kaf[ks][0] = *(const bf16x8*)(Kh + aro + ks * 32 + qd * 8);
      kaf[ks][1] = *(const bf16x8*)(Kl + aro + ks * 32 + qd * 8);
    }
  }

  // staging slot: row tid>>2, columns (tid&3)*16 .. +15  (two bf16x8/plane)
  const int srow = tid >> 2, scol = (tid & 3) * 16;

  bf16x8 kh8a, kh8b, kl8a, kl8b, qh8a, qh8b, ql8a, ql8b, vt8a, vt8b;
  {
    const int s0 = zb * 4 * 64;
    const size_t off = ((size_t)bh * L + s0 + srow) * E + scol;
    kh8a = *(const bf16x8*)(Kh + off);   kh8b = *(const bf16x8*)(Kh + off + 8);
    kl8a = *(const bf16x8*)(Kl + off);   kl8b = *(const bf16x8*)(Kl + off + 8);
    qh8a = *(const bf16x8*)(Qh + off);   qh8b = *(const bf16x8*)(Qh + off + 8);
    ql8a = *(const bf16x8*)(Ql + off);   ql8b = *(const bf16x8*)(Ql + off + 8);
    const size_t voff = ((size_t)bh * E + srow) * L + s0 + scol;
    vt8a = *(const bf16x8*)(VT + voff);  vt8b = *(const bf16x8*)(VT + voff + 8);
  }

  f32x4 accv[4] = {};
  float ent[4] = {0.f, 0.f, 0.f, 0.f};  // log2 domain

#pragma unroll
  for (int it = 0; it < 4; ++it) {
    const int s0 = (zb * 4 + it) * 64;
    const int s0n = ((zb * 4 + it + 1) & 15) * 64;

    __syncthreads();  // prior-iter LDS reads done (prefetch loads long-complete)
    *(bf16x8*)&Kh_s[srow][scol]     = kh8a;
    *(bf16x8*)&Kh_s[srow][scol + 8] = kh8b;
    *(bf16x8*)&Kl_s[srow][scol]     = kl8a;
    *(bf16x8*)&Kl_s[srow][scol + 8] = kl8b;
    *(bf16x8*)&Qh_s[srow][scol]     = qh8a;
    *(bf16x8*)&Qh_s[srow][scol + 8] = qh8b;
    *(bf16x8*)&Ql_s[srow][scol]     = ql8a;
    *(bf16x8*)&Ql_s[srow][scol + 8] = ql8b;
    *(bf16x8*)&Vt_s[srow][scol]     = vt8a;
    *(bf16x8*)&Vt_s[srow][scol + 8] = vt8b;
    __syncthreads();  // staged tile visible

    // ---- prefetch it+1 NOW: a full compute phase before the next barrier ----
    {
      const size_t off = ((size_t)bh * L + s0n + srow) * E + scol;
      kh8a = *(const bf16x8*)(Kh + off);   kh8b = *(const bf16x8*)(Kh + off + 8);
      kl8a = *(const bf16x8*)(Kl + off);   kl8b = *(const bf16x8*)(Kl + off + 8);
      qh8a = *(const bf16x8*)(Qh + off);   qh8b = *(const bf16x8*)(Qh + off + 8);
      ql8a = *(const bf16x8*)(Ql + off);   ql8b = *(const bf16x8*)(Ql + off + 8);
      const size_t voff = ((size_t)bh * E + srow) * L + s0n + scol;
      vt8a = *(const bf16x8*)(VT + voff);  vt8b = *(const bf16x8*)(VT + voff + 8);
    }

    // ---- dual QK^T: T1 = Q[l]·K[s], T2 = K[l]·Q[s] (same C-layout).
    // Term order matched so the diagonal cancels bitwise (Aa == 0).
    f32x4 acc1[2] = {}, acc2[2] = {};
#pragma unroll
    for (int nt = 0; nt < 2; ++nt) {
      const int brow = sh * 32 + nt * 16 + c;
#pragma unroll
      for (int ks = 0; ks < 2; ++ks) {
        bf16x8 kbh = *(const bf16x8*)&Kh_s[brow][ks * 32 + qd * 8];
        bf16x8 kbl = *(const bf16x8*)&Kl_s[brow][ks * 32 + qd * 8];
        bf16x8 qbh = *(const bf16x8*)&Qh_s[brow][ks * 32 + qd * 8];
        bf16x8 qbl = *(const bf16x8*)&Ql_s[brow][ks * 32 + qd * 8];
        acc1[nt] = mfma16(qaf[ks][0], kbh, acc1[nt]);
        acc1[nt] = mfma16(qaf[ks][0], kbl, acc1[nt]);
        acc1[nt] = mfma16(qaf[ks][1], kbh, acc1[nt]);
        acc2[nt] = mfma16(kaf[ks][0], qbh, acc2[nt]);
        acc2[nt] = mfma16(kaf[ks][1], qbh, acc2[nt]);
        acc2[nt] = mfma16(kaf[ks][0], qbl, acc2[nt]);
      }
    }

    // ---- transform (register-local), att NT-store, attL, entropy ----
    float* arow = attg + ((size_t)bh * L + l0 + lh * 16 + qd * 4) * L + s0 + sh * 32;
#pragma unroll
    for (int nt = 0; nt < 2; ++nt) {
#pragma unroll
      for (int r = 0; r < 4; ++r) {
        float u = acc1[nt][r] + acc2[nt][r];        // 16*S_sym
        float d = acc1[nt][r] - acc2[nt][r];        // 16*A_anti
        float r1 = rcp_fast(exp2_fast(u * A1) + 1.f);
        float gate = rcp_fast(1.f + exp2_fast(fmaf(r1, G1m2, G1)));
        float r2 = rcp_fast(exp2_fast(d * A2) + 1.f);
        float dir  = rcp_fast(1.f + exp2_fast(fmaf(r2, G2m2, G2)));
        float t    = fmaf(rcp_fast(exp2_fast(d * A3) + 1.f), -2.f, 1.f);
        float a = fmaxf(t, 0.0f) * gate * dir;
        ent[r] -= a * log2_fast(fmaxf(a, 1e-8f));
        __builtin_nontemporal_store(a, arow + (size_t)r * L + nt * 16 + c);
        attL[w * 16 + qd * 4 + r][nt * 16 + c] = (bf16_t)a;
      }
    }
    // wave-local D->A exchange: LDS-only drain; globals stay in flight.
    asm volatile("s_waitcnt lgkmcnt(0)" ::: "memory");

    // ---- PV ----
    bf16x8 af = *(const bf16x8*)&attL[w * 16 + c][qd * 8];
#pragma unroll
    for (int ne = 0; ne < 4; ++ne) {
      bf16x8 bv = *(const bf16x8*)&Vt_s[ne * 16 + c][sh * 32 + qd * 8];
      accv[ne] = mfma16(af, bv, accv[ne]);
    }
  }

  // ---- epilogue: combine s-halves, atomic into global (zb-split blocks) ----
  __syncthreads();  // all LDS reads done before red aliases Kh_s
  float (*red)[68] = (float(*)[68])smem;
  if (sh == 1) {
#pragma unroll
    for (int ne = 0; ne < 4; ++ne)
#pragma unroll
      for (int r = 0; r < 4; ++r)
        red[lh * 16 + qd * 4 + r][ne * 16 + c] = accv[ne][r];
  }
  __syncthreads();
  if (sh == 0) {
#pragma unroll
    for (int ne = 0; ne < 4; ++ne)
#pragma unroll
      for (int r = 0; r < 4; ++r) {
        float val = accv[ne][r] + red[lh * 16 + qd * 4 + r][ne * 16 + c];
        atomicAdd(Vout + ((size_t)(b * L + l0 + lh * 16 + qd * 4 + r) * H + h) * E +
                      ne * 16 + c,
                  val);
      }
  }
#pragma unroll
  for (int r = 0; r < 4; ++r) {
    float e = ent[r];
    e += __shfl_xor(e, 1);
    e += __shfl_xor(e, 2);
    e += __shfl_xor(e, 4);
    e += __shfl_xor(e, 8);
    if (c == 0)
      atomicAdd(entr + (size_t)bh * L + l0 + lh * 16 + qd * 4 + r, e * LN2);
  }
}

// ===========================================================================
// Fallback (R2 kernel) if ws_size is too small for the planes.
// ===========================================================================
__device__ __forceinline__ float tanh_fast(float x) {
  return 1.0f - 2.0f * rcp_fast(__expf(2.0f * x) + 1.0f);
}
__device__ __forceinline__ float sigm_fast(float x) {
  return rcp_fast(1.0f + __expf(-x));
}
__device__ __forceinline__ void split_store(bf16_t* hi, bf16_t* lo, float4 x) {
  bf16x4 hv, lv;
  split4(x, hv, lv);
  *(bf16x4*)hi = hv;
  *(bf16x4*)lo = lv;
}

__global__ __launch_bounds__(128, 1) void fused_attn(
    const float* __restrict__ q, const float* __restrict__ kk,
    const float* __restrict__ v,
    float* __restrict__ Vout, float* __restrict__ attg, float* __restrict__ entr,
    const float* __restrict__ p_lgg, const float* __restrict__ p_ltg,
    const float* __restrict__ p_lgd, const float* __restrict__ p_ltd)
{
  constexpr int TM = 32;
  __shared__ bf16_t Qa_hi[TM][72], Qa_lo[TM][72];
  __shared__ bf16_t Ka_hi[TM][72], Ka_lo[TM][72];
  __shared__ bf16_t KQ_hi[64][72], KQ_lo[64][72];
  __shared__ bf16_t Vts[64][72];
  __shared__ float  T2ex[2][64][17];
  __shared__ bf16_t attLs[2][16][72];

  const int tid = threadIdx.x;
  const int w = tid >> 6;
  const int lane = tid & 63;
  const int c = lane & 15;
  const int qd = lane >> 4;
  const int t8 = tid >> 4;
  const int c4 = tid & 15;
  const int lt = blockIdx.x;
  const int bh = blockIdx.y;
  const int b = bh >> 3, h = bh & 7;
  const int l0 = lt * TM;

  const float gg = fminf(fmaxf(__expf(p_lgg[0]), 1e-3f), 20.0f);
  const float tg = fminf(fmaxf(__expf(p_ltg[0]), 1e-3f), 10.0f);
  const float gd = fminf(fmaxf(__expf(p_lgd[0]), 1e-3f), 20.0f);
  const float td = fminf(fmaxf(__expf(p_ltd[0]), 1e-3f), 10.0f);
  const float inv_tg = 1.0f / tg;
  const float inv_td = 1.0f / td;
  const float gd_inv_td = gd * inv_td;

  const float* qlbase = q  + ((size_t)(b * L + l0) * H + h) * E;
  const float* qsbase = q  + ((size_t)b * L * H + h) * E;
  const float* kbase  = kk + ((size_t)b * L * H + h) * E;
  const float* vbase  = v  + ((size_t)b * L * H + h) * E;

#pragma unroll
  for (int i = 0; i < 4; ++i) {
    int r = t8 + 8 * i;
    float4 qa = *(const float4*)(qlbase + (size_t)r * HE + c4 * 4);
    float4 ka = *(const float4*)(kbase + (size_t)(l0 + r) * HE + c4 * 4);
    split_store(&Qa_hi[r][c4 * 4], &Qa_lo[r][c4 * 4], qa);
    split_store(&Ka_hi[r][c4 * 4], &Ka_lo[r][c4 * 4], ka);
  }

  float4 kpre[8], qpre[8];
  float vpre[32];
#pragma unroll
  for (int i = 0; i < 8; ++i)
    kpre[i] = *(const float4*)(kbase + (size_t)(t8 + 8 * i) * HE + c4 * 4);
#pragma unroll
  for (int i = 0; i < 8; ++i)
    qpre[i] = *(const float4*)(qsbase + (size_t)(t8 + 8 * i) * HE + c4 * 4);
#pragma unroll
  for (int j = 0; j < 32; ++j)
    vpre[j] = vbase[(size_t)(w * 32 + j) * HE + lane];

  __syncthreads();

  bf16x8 qaf[2][2], kaf[2][2];
#pragma unroll
  for (int ks = 0; ks < 2; ++ks) {
    qaf[ks][0] = *(const bf16x8*)&Qa_hi[w * 16 + c][ks * 32 + qd * 8];
    qaf[ks][1] = *(const bf16x8*)&Qa_lo[w * 16 + c][ks * 32 + qd * 8];
    kaf[ks][0] = *(const bf16x8*)&Ka_hi[w * 16 + c][ks * 32 + qd * 8];
    kaf[ks][1] = *(const bf16x8*)&Ka_lo[w * 16 + c][ks * 32 + qd * 8];
  }

  f32x4 accv[4] = {};
  float ent[4] = {0.f, 0.f, 0.f, 0.f};
  const int gl_base = l0 + w * 16 + qd * 4;

  for (int it = 0; it < 16; ++it) {
    const int s0 = it * 64;
    const int snext = ((it + 1) & 15) * 64;

    __syncthreads();
#pragma unroll
    for (int i = 0; i < 8; ++i) {
      int r = t8 + 8 * i;
      split_store(&KQ_hi[r][c4 * 4], &KQ_lo[r][c4 * 4], kpre[i]);
    }
#pragma unroll
    for (int j = 0; j < 16; ++j) {
      bf16x2 p;
      p[0] = (bf16_t)vpre[2 * j];
      p[1] = (bf16_t)vpre[2 * j + 1];
      *(bf16x2*)&Vts[lane][w * 32 + 2 * j] = p;
    }
    __syncthreads();

#pragma unroll
    for (int i = 0; i < 8; ++i)
      kpre[i] = *(const float4*)(kbase + (size_t)(snext + t8 + 8 * i) * HE + c4 * 4);
#pragma unroll
    for (int j = 0; j < 32; ++j)
      vpre[j] = vbase[(size_t)(snext + w * 32 + j) * HE + lane];

    f32x4 acc1[4] = {};
#pragma unroll
    for (int nt = 0; nt < 4; ++nt) {
#pragma unroll
      for (int ks = 0; ks < 2; ++ks) {
        bf16x8 bhv = *(const bf16x8*)&KQ_hi[nt * 16 + c][ks * 32 + qd * 8];
        bf16x8 blv = *(const bf16x8*)&KQ_lo[nt * 16 + c][ks * 32 + qd * 8];
        acc1[nt] = mfma16(qaf[ks][0], bhv, acc1[nt]);
        acc1[nt] = mfma16(qaf[ks][0], blv, acc1[nt]);
        acc1[nt] = mfma16(qaf[ks][1], bhv, acc1[nt]);
      }
    }
    __syncthreads();

#pragma unroll
    for (int i = 0; i < 8; ++i) {
      int r = t8 + 8 * i;
      split_store(&KQ_hi[r][c4 * 4], &KQ_lo[r][c4 * 4], qpre[i]);
    }
    __syncthreads();

#pragma unroll
    for (int i = 0; i < 8; ++i)
      qpre[i] = *(const float4*)(qsbase + (size_t)(snext + t8 + 8 * i) * HE + c4 * 4);

    f32x4 acc2[4] = {};
#pragma unroll
    for (int mt = 0; mt < 4; ++mt) {
#pragma unroll
      for (int ks = 0; ks < 2; ++ks) {
        bf16x8 ahv = *(const bf16x8*)&KQ_hi[mt * 16 + c][ks * 32 + qd * 8];
        bf16x8 alv = *(const bf16x8*)&KQ_lo[mt * 16 + c][ks * 32 + qd * 8];
        acc2[mt] = mfma16(ahv, kaf[ks][0], acc2[mt]);
        acc2[mt] = mfma16(ahv, kaf[ks][1], acc2[mt]);
        acc2[mt] = mfma16(alv, kaf[ks][0], acc2[mt]);
      }
    }

#pragma unroll
    for (int mt = 0; mt < 4; ++mt)
#pragma unroll
      for (int r = 0; r < 4; ++r)
        T2ex[w][mt * 16 + qd * 4 + r][c] = acc2[mt][r];
    __syncthreads();

    float* attrow0 = attg + ((size_t)bh * L + gl_base) * L + s0;
#pragma unroll
    for (int nt = 0; nt < 4; ++nt) {
#pragma unroll
      for (int r = 0; r < 4; ++r) {
        float x = 0.125f * acc1[nt][r];
        float y = 0.125f * T2ex[w][nt * 16 + c][qd * 4 + r];
        float Ss = 0.5f * (x + y);
        float Aa = 0.5f * (x - y);
        float gate = sigm_fast(gg * tanh_fast(Ss * inv_tg));
        float dir  = sigm_fast(gd * tanh_fast(Aa * inv_td));
        float t    = tanh_fast(Aa * gd_inv_td);
        float a = fmaxf(t, 0.0f) * gate * dir;
        ent[r] -= a * __logf(fmaxf(a, 1e-8f));
        attrow0[(size_t)r * L + nt * 16 + c] = a;
        attLs[w][qd * 4 + r][nt * 16 + c] = (bf16_t)a;
      }
    }
    __syncthreads();

#pragma unroll
    for (int ks = 0; ks < 2; ++ks) {
      bf16x8 af = *(const bf16x8*)&attLs[w][c][ks * 32 + qd * 8];
#pragma unroll
      for (int ne = 0; ne < 4; ++ne) {
        bf16x8 bfv = *(const bf16x8*)&Vts[ne * 16 + c][ks * 32 + qd * 8];
        accv[ne] = mfma16(af, bfv, accv[ne]);
      }
    }
  }

#pragma unroll
  for (int r = 0; r < 4; ++r) {
    float* vb = Vout + ((size_t)(b * L + gl_base + r) * H + h) * E;
#pragma unroll
    for (int ne = 0; ne < 4; ++ne) vb[ne * 16 + c] = accv[ne][r];
    float e4 = ent[r];
    e4 += __shfl_xor(e4, 1);
    e4 += __shfl_xor(e4, 2);
    e4 += __shfl_xor(e4, 4);
    e4 += __shfl_xor(e4, 8);
    if (c == 0) entr[(size_t)bh * L + gl_base + r] = e4;
  }
}

}  // namespace

extern "C" void kernel_launch(void* const* d_in, const int* in_sizes, int n_in,
                              void* d_out, int out_size, void* d_ws, size_t ws_size,
                              hipStream_t stream) {
  const float* q = (const float*)d_in[0];
  const float* k = (const float*)d_in[1];
  const float* v = (const float*)d_in[2];
  const float* p_lgg = (const float*)d_in[7];
  const float* p_ltg = (const float*)d_in[8];
  const float* p_lgd = (const float*)d_in[9];
  const float* p_ltd = (const float*)d_in[10];

  float* Vout = (float*)d_out;          // (B,L,H,E)   1,048,576
  float* att  = Vout + 1048576;         // (B,H,L,S)  16,777,216
  float* entr = att + 16777216;         // (B,H,L)        16,384

  const size_t need = 5 * PL * sizeof(bf16_t);  // 10,485,760 B
  if (ws_size >= need) {
    bf16_t* ws = (bf16_t*)d_ws;
    k_prep<<<dim3(1296), 256, 0, stream>>>(q, k, v, ws, Vout, entr);
    k_main<<<dim3(32, 16, 4), 256, 0, stream>>>(
        ws, Vout, att, entr, p_lgg, p_ltg, p_lgd, p_ltd);
  } else {
    fused_attn<<<dim3(32, 16), 128, 0, stream>>>(
        q, k, v, Vout, att, entr, p_lgg, p_ltg, p_lgd, p_ltd);
  }
}